// Round 10
// baseline (328.864 us; speedup 1.0000x reference)
//
#include <hip/hip_runtime.h>

// Problem constants
#define Bc   2
#define Sc   1024
#define Hc   2048
#define NHc  16
#define NKVc 4
#define HDc  128
#define KBc  1024
#define NREPc 4

typedef unsigned short ushort_t;
typedef unsigned int uint32;
typedef __attribute__((ext_vector_type(8))) __bf16 bf16x8;
typedef __attribute__((ext_vector_type(4))) float f32x4;

static __device__ __forceinline__ size_t dsz(int x) { return (size_t)x; }

static __device__ __forceinline__ ushort_t f2bf(float f) {
  uint32 u = __float_as_uint(f);
  u += 0x7fffu + ((u >> 16) & 1u);        // round-to-nearest-even
  return (ushort_t)(u >> 16);
}
static __device__ __forceinline__ float bf2f(ushort_t u) {
  return __uint_as_float(((uint32)u) << 16);
}

#define ROPE_INV 0.14391156831212787f   // ln(10000)/64
#define QSCALE   (0.08838834764831845f * 1.4426950408889634f)  // scale*log2e

// ---------------------------------------------------------------------------
// Fused fp32 -> bf16 conversion of all 6 inputs (one dispatch).
// ---------------------------------------------------------------------------
#define FSEG 1048576
__global__ void conv_all(const float* __restrict__ x,  const float* __restrict__ Wq,
                         const float* __restrict__ Wqn, const float* __restrict__ Wk,
                         const float* __restrict__ Wv,  const float* __restrict__ Wo,
                         ushort_t* xb, ushort_t* Wqb, ushort_t* Wqnb,
                         ushort_t* Wkb, ushort_t* Wvb, ushort_t* Wob)
{
  int i = blockIdx.x * 256 + threadIdx.x;      // f4 index, < 4.5*FSEG
  const float* s; ushort_t* d; int off;
  if      (i <     FSEG)            { s = x;   d = xb;   off = i; }
  else if (i < 2 * FSEG)            { s = Wq;  d = Wqb;  off = i - FSEG; }
  else if (i < 3 * FSEG)            { s = Wqn; d = Wqnb; off = i - 2 * FSEG; }
  else if (i < 3 * FSEG + FSEG / 4) { s = Wk;  d = Wkb;  off = i - 3 * FSEG; }
  else if (i < 3 * FSEG + FSEG / 2) { s = Wv;  d = Wvb;  off = i - 3 * FSEG - FSEG / 4; }
  else                              { s = Wo;  d = Wob;  off = i - 3 * FSEG - FSEG / 2; }
  float4 v = ((const float4*)s)[off];
  ushort4 o;
  o.x = f2bf(v.x); o.y = f2bf(v.y); o.z = f2bf(v.z); o.w = f2bf(v.w);
  ((ushort4*)d)[off] = o;
}

// ---------------------------------------------------------------------------
// global_load_lds helper
// ---------------------------------------------------------------------------
#define GL16(gsrc, ldst)                                                \
  __builtin_amdgcn_global_load_lds(                                     \
      (const __attribute__((address_space(1))) void*)(gsrc),            \
      (__attribute__((address_space(3))) void*)(ldst), 16, 0, 0)

// ---------------------------------------------------------------------------
// Fused projection GEMM (one dispatch, 640 blocks): C = xb * W^T for
// {Wq->qb, Wqn->qnb(*QSCALE), Wk->kkvb, Wv->vkvb}, bf16 outputs.
// ---------------------------------------------------------------------------
__global__ __launch_bounds__(256) void gemm_proj(
    const ushort_t* __restrict__ A,    // xb [2048][2048]
    const ushort_t* __restrict__ Wqb,  const ushort_t* __restrict__ Wqnb,
    const ushort_t* __restrict__ Wkb,  const ushort_t* __restrict__ Wvb,
    ushort_t* __restrict__ qb, ushort_t* __restrict__ qnb,
    ushort_t* __restrict__ kkvb, ushort_t* __restrict__ vkvb)
{
  __shared__ ushort_t sA[128 * 32];
  __shared__ ushort_t sB[128 * 32];

  const int K = Hc;                    // 2048
  const int bx = blockIdx.x;
  const ushort_t* Bseg; ushort_t* Cseg; int segN, colseg; float scale;
  if      (bx < 16) { Bseg = Wqb;  Cseg = qb;   segN = 2048; colseg = bx * 128;        scale = 1.f; }
  else if (bx < 32) { Bseg = Wqnb; Cseg = qnb;  segN = 2048; colseg = (bx - 16) * 128; scale = QSCALE; }
  else if (bx < 36) { Bseg = Wkb;  Cseg = kkvb; segN = 512;  colseg = (bx - 32) * 128; scale = 1.f; }
  else              { Bseg = Wvb;  Cseg = vkvb; segN = 512;  colseg = (bx - 36) * 128; scale = 1.f; }

  const int tid  = threadIdx.x;
  const int lane = tid & 63;
  const int wid  = tid >> 6;
  const int wr   = wid >> 1;
  const int wc   = wid & 1;
  const int row0 = blockIdx.y * 128;
  const int fr = lane & 15;
  const int fq = lane >> 4;

  f32x4 acc[4][4];
  #pragma unroll
  for (int m = 0; m < 4; ++m)
    #pragma unroll
    for (int n = 0; n < 4; ++n) acc[m][n] = (f32x4){0.f, 0.f, 0.f, 0.f};

  const int rS = tid >> 2;
  const int kg = (tid & 3) * 8;
  const ushort_t* Asrc0 = A + dsz(row0 + rS) * K + kg;
  const ushort_t* Asrc1 = A + dsz(row0 + 64 + rS) * K + kg;
  const ushort_t* Bsrc0 = Bseg + dsz(colseg + rS) * K + kg;
  const ushort_t* Bsrc1 = Bseg + dsz(colseg + 64 + rS) * K + kg;
  char* ldsA0 = (char*)sA + tid * 16;
  char* ldsA1 = (char*)sA + 4096 + tid * 16;
  char* ldsB0 = (char*)sB + tid * 16;
  char* ldsB1 = (char*)sB + 4096 + tid * 16;

  for (int k0 = 0; k0 < K; k0 += 32) {
    GL16(Asrc0 + k0, ldsA0);
    GL16(Asrc1 + k0, ldsA1);
    GL16(Bsrc0 + k0, ldsB0);
    GL16(Bsrc1 + k0, ldsB1);
    __syncthreads();

    bf16x8 a[4], b[4];
    #pragma unroll
    for (int m = 0; m < 4; ++m)
      a[m] = *(const bf16x8*)&sA[(wr * 64 + m * 16 + fr) * 32 + fq * 8];
    #pragma unroll
    for (int n = 0; n < 4; ++n)
      b[n] = *(const bf16x8*)&sB[(wc * 64 + n * 16 + fr) * 32 + fq * 8];
    #pragma unroll
    for (int m = 0; m < 4; ++m)
      #pragma unroll
      for (int n = 0; n < 4; ++n)
        acc[m][n] = __builtin_amdgcn_mfma_f32_16x16x32_bf16(a[m], b[n], acc[m][n], 0, 0, 0);
    __syncthreads();
  }

  #pragma unroll
  for (int m = 0; m < 4; ++m)
    #pragma unroll
    for (int n = 0; n < 4; ++n)
      #pragma unroll
      for (int j = 0; j < 4; ++j)
        Cseg[dsz(row0 + wr * 64 + m * 16 + fq * 4 + j) * segN +
             colseg + wc * 64 + n * 16 + fr] = f2bf(acc[m][n][j] * scale);
}

// ---------------------------------------------------------------------------
// Generic bf16 GEMM with f32 output (final Wo projection).
// ---------------------------------------------------------------------------
__global__ __launch_bounds__(256) void gemm_bt_bf16(
    const ushort_t* __restrict__ A, const ushort_t* __restrict__ B,
    float* __restrict__ C, int M, int N, int K)
{
  __shared__ ushort_t sA[128 * 32];
  __shared__ ushort_t sB[128 * 32];

  const int tid  = threadIdx.x;
  const int lane = tid & 63;
  const int wid  = tid >> 6;
  const int wr   = wid >> 1;
  const int wc   = wid & 1;
  const int row0 = blockIdx.y * 128;
  const int col0 = blockIdx.x * 128;
  const int fr = lane & 15;
  const int fq = lane >> 4;

  f32x4 acc[4][4];
  #pragma unroll
  for (int m = 0; m < 4; ++m)
    #pragma unroll
    for (int n = 0; n < 4; ++n) acc[m][n] = (f32x4){0.f, 0.f, 0.f, 0.f};

  const int rS = tid >> 2;
  const int kg = (tid & 3) * 8;
  const ushort_t* Asrc0 = A + dsz(row0 + rS) * K + kg;
  const ushort_t* Asrc1 = A + dsz(row0 + 64 + rS) * K + kg;
  const ushort_t* Bsrc0 = B + dsz(col0 + rS) * K + kg;
  const ushort_t* Bsrc1 = B + dsz(col0 + 64 + rS) * K + kg;
  char* ldsA0 = (char*)sA + tid * 16;
  char* ldsA1 = (char*)sA + 4096 + tid * 16;
  char* ldsB0 = (char*)sB + tid * 16;
  char* ldsB1 = (char*)sB + 4096 + tid * 16;

  for (int k0 = 0; k0 < K; k0 += 32) {
    GL16(Asrc0 + k0, ldsA0);
    GL16(Asrc1 + k0, ldsA1);
    GL16(Bsrc0 + k0, ldsB0);
    GL16(Bsrc1 + k0, ldsB1);
    __syncthreads();

    bf16x8 a[4], b[4];
    #pragma unroll
    for (int m = 0; m < 4; ++m)
      a[m] = *(const bf16x8*)&sA[(wr * 64 + m * 16 + fr) * 32 + fq * 8];
    #pragma unroll
    for (int n = 0; n < 4; ++n)
      b[n] = *(const bf16x8*)&sB[(wc * 64 + n * 16 + fr) * 32 + fq * 8];
    #pragma unroll
    for (int m = 0; m < 4; ++m)
      #pragma unroll
      for (int n = 0; n < 4; ++n)
        acc[m][n] = __builtin_amdgcn_mfma_f32_16x16x32_bf16(a[m], b[n], acc[m][n], 0, 0, 0);
    __syncthreads();
  }

  #pragma unroll
  for (int m = 0; m < 4; ++m)
    #pragma unroll
    for (int n = 0; n < 4; ++n)
      #pragma unroll
      for (int j = 0; j < 4; ++j)
        C[dsz(row0 + wr * 64 + m * 16 + fq * 4 + j) * N +
          col0 + wc * 64 + n * 16 + fr] = acc[m][n][j];
}

// ---------------------------------------------------------------------------
// RoPE cos/sin table: tab[r][j] = (cos, sin) of pos[r] * invfreq[j].
// 2048 x 64 float2 = 1MB. Built once per call; consumed by rope kernels.
// ---------------------------------------------------------------------------
__global__ void rope_tab(const int* __restrict__ pos, float2* __restrict__ tab)
{
  int idx = blockIdx.x * 256 + threadIdx.x;   // 131072
  int j = idx & 63;
  int r = idx >> 6;
  float p = (float)pos[r];
  float f = p * expf(-(float)j * ROPE_INV);
  float2 cs; cs.x = cosf(f); cs.y = sinf(f);
  tab[idx] = cs;
}

// RoPE in-place on bf16 qb, folds in QSCALE (table-driven).
__global__ void rope_q_ip(ushort_t* __restrict__ qb, const float2* __restrict__ tab)
{
  int idx = blockIdx.x * blockDim.x + threadIdx.x;   // 2M
  int j = idx & 63;
  int h = (idx >> 6) & 15;
  int r = idx >> 10;
  float2 cs = tab[r * 64 + j];
  ushort_t* d = qb + dsz(r) * (NHc * HDc) + h * HDc;
  float x1 = bf2f(d[j]), x2 = bf2f(d[j + 64]);
  d[j]      = f2bf((x1 * cs.x - x2 * cs.y) * QSCALE);
  d[j + 64] = f2bf((x2 * cs.x + x1 * cs.y) * QSCALE);
}

// RoPE self-k (bf16 in) -> Kcat rows 1024..2047 (table-driven)
__global__ void rope_k_kcat(const ushort_t* __restrict__ kkvb, const float2* __restrict__ tab,
                            ushort_t* __restrict__ Kcat)
{
  int idx = blockIdx.x * blockDim.x + threadIdx.x;   // 512K
  int j = idx & 63;
  int kvh = (idx >> 6) & 3;
  int s = (idx >> 8) & 1023;
  int b = idx >> 18;
  float2 cs = tab[(b * Sc + s) * 64 + j];
  const ushort_t* src = kkvb + dsz(b * Sc + s) * (NKVc * HDc) + kvh * HDc;
  ushort_t* dst = Kcat + (dsz(b * NKVc + kvh) * 2048 + 1024 + s) * HDc;
  float x1 = bf2f(src[j]), x2 = bf2f(src[j + 64]);
  dst[j]      = f2bf(x1 * cs.x - x2 * cs.y);
  dst[j + 64] = f2bf(x2 * cs.x + x1 * cs.y);
}

// kb_keys fp32 -> Kcat rows 0..1023 bf16
__global__ void kb_kcat(const float* __restrict__ src, ushort_t* __restrict__ Kcat)
{
  int i = blockIdx.x * blockDim.x + threadIdx.x;     // 262144
  int d4 = i & 31;
  int kvh = (i >> 5) & 3;
  int k = (i >> 7) & 1023;
  int b = i >> 17;
  float4 v = *(const float4*)&src[dsz(b * KBc + k) * (NKVc * HDc) + kvh * HDc + d4 * 4];
  ushort4 o;
  o.x = f2bf(v.x); o.y = f2bf(v.y); o.z = f2bf(v.z); o.w = f2bf(v.w);
  *(ushort4*)&Kcat[(dsz(b * NKVc + kvh) * 2048 + k) * HDc + d4 * 4] = o;
}

// Build Vt[b][kvh][128][2048] from kb_values (f32) + vkvb (bf16)
__global__ __launch_bounds__(256) void vt_build(const float* __restrict__ kbv,
                                                const ushort_t* __restrict__ vkvb,
                                                ushort_t* __restrict__ Vt)
{
  __shared__ float sT[32][33];
  const int k0 = blockIdx.x * 32;
  const int d0 = blockIdx.y * 32;
  const int bk = blockIdx.z;
  const int b = bk >> 2, kvh = bk & 3;
  const int tid = threadIdx.x;

  #pragma unroll
  for (int t = 0; t < 4; ++t) {
    int li = tid + t * 256;
    int kk = li >> 5, dl = li & 31;
    int kg = k0 + kk;
    float v = (kg < 1024)
      ? kbv[dsz(b * KBc + kg) * (NKVc * HDc) + kvh * HDc + d0 + dl]
      : bf2f(vkvb[dsz(b * Sc + kg - 1024) * (NKVc * HDc) + kvh * HDc + d0 + dl]);
    sT[kk][dl] = v;
  }
  __syncthreads();
  #pragma unroll
  for (int t = 0; t < 4; ++t) {
    int li = tid + t * 256;
    int dl = li >> 5, kk = li & 31;
    Vt[(dsz(b * NKVc + kvh) * HDc + d0 + dl) * 2048 + k0 + kk] = f2bf(sT[kk][dl]);
  }
}

// ---------------------------------------------------------------------------
// Attention v7: 4 waves x 32 queries (2 subgroups of 16 sharing K/V frags),
// 256-thread blocks, 32KB shared dbuf, 3-way KV split. Grid (256, 3) =
// exactly 3 blocks/CU, 12 waves/CU. Halves per-wave LDS read traffic vs v6.
// ---------------------------------------------------------------------------
__global__ __launch_bounds__(256, 3) void attn_mfma7(
    const ushort_t* __restrict__ Qr,   // roped q (pre-scaled), (B*S, 2048)
    const ushort_t* __restrict__ Qn,   // q_new (pre-scaled), (B*S, 2048)
    const ushort_t* __restrict__ Kcat, // (B, NKV, 2048, 128)
    const ushort_t* __restrict__ Vt,   // (B, NKV, 128, 2048)
    ushort_t* __restrict__ Opart,      // [3][256][128][128] bf16
    float* __restrict__ mlpart)        // [3][256][128][2]
{
  __shared__ ushort_t sK[2][32 * 128];   // 8KB/buf, rows XOR-swizzled
  __shared__ ushort_t sV[2][128 * 32];   // 8KB/buf, slots XOR-swizzled

  const int tid = threadIdx.x;
  const int lane = tid & 63;
  const int w = tid >> 6;                // 0..3
  const int fr = lane & 15;
  const int fq = lane >> 4;
  const int blk = blockIdx.x;            // (b,h,qt): qt 0..7
  const int third = blockIdx.y;          // 0..2
  const int qt = blk & 7;
  const int h  = (blk >> 3) & 15;
  const int b  = blk >> 7;
  const int kvh = h >> 2;
  const int qrow0 = qt * 128 + w * 32 + fr;   // subgroup 0
  const int qrow1 = qrow0 + 16;               // subgroup 1
  const int kperm = ((fr >> 2) << 3) + (fr & 3);   // u(kperm) = fr

  const ushort_t* Kb = Kcat + dsz(b * NKVc + kvh) * 2048 * HDc;
  const ushort_t* Vb = Vt   + dsz(b * NKVc + kvh) * HDc * 2048;

  const int nt  = 36 + 4 * qt;           // key tiles (keys = 1024 + (qt+1)*128)
  const int q3 = nt / 3, r3 = nt % 3;
  const int t_lo = third * q3 + (third < r3 ? third : r3);
  const int t_hi = t_lo + q3 + (third < r3 ? 1 : 0);

  // staging offsets (R6-verified, conflict-free): 256 threads, 2 GL16 each
  // for K (rows 0..15 / 16..31) and V (rows 0..63 / 64..127).
  const int kr0 = tid >> 4;
  const int ks0 = tid & 15;
  const int ku0 = (kr0 & 3) | ((kr0 >> 3) << 2);
  const int kOffA = kr0 * 256 + ((ks0 ^ ku0) * 16);
  const int kOffB = (kr0 + 16) * 256 + ((ks0 ^ (ku0 + 8)) * 16);
  const int vr0 = tid >> 2;
  const int vs0 = tid & 3;
  const int vu0 = (vr0 >> 1) & 3;
  const size_t vOffA = (size_t)vr0 * 4096 + ((vs0 ^ vu0) * 16);
  const size_t vOffB = vOffA + (size_t)64 * 4096;

  const int vslot = (fq ^ ((fr >> 1) & 3)) * 8;

#define STAGE(bi, t)                                                   \
  {                                                                    \
    const char* kgb = (const char*)Kb + (size_t)(t) * 8192;            \
    const char* vgb = (const char*)Vb + (size_t)(t) * 64;              \
    GL16(kgb + kOffA, (char*)&sK[bi][0] + tid * 16);                   \
    GL16(kgb + kOffB, (char*)&sK[bi][0] + 4096 + tid * 16);            \
    GL16(vgb + vOffA, (char*)&sV[bi][0] + tid * 16);                   \
    GL16(vgb + vOffB, (char*)&sV[bi][0] + 4096 + tid * 16);            \
  }

  // Q fragments for the starting phase (both subgroups)
  bf16x8 qf0[4], qf1[4];
  {
    const ushort_t* base = (t_lo >= 32 ? Qr : Qn);
    const ushort_t* p0 = base + dsz(b * Sc + qrow0) * (NHc * HDc) + h * HDc;
    const ushort_t* p1 = base + dsz(b * Sc + qrow1) * (NHc * HDc) + h * HDc;
    #pragma unroll
    for (int c = 0; c < 4; ++c) {
      qf0[c] = *(const bf16x8*)&p0[c * 32 + fq * 8];
      qf1[c] = *(const bf16x8*)&p1[c * 32 + fq * 8];
    }
  }

  float m0 = -1e30f, l0 = 0.f, m1 = -1e30f, l1 = 0.f;
  f32x4 ot0[8], ot1[8];
  #pragma unroll
  for (int dt = 0; dt < 8; ++dt) {
    ot0[dt] = (f32x4){0.f, 0.f, 0.f, 0.f};
    ot1[dt] = (f32x4){0.f, 0.f, 0.f, 0.f};
  }

  STAGE(0, t_lo);
  __syncthreads();

  for (int t = t_lo; t < t_hi; ++t) {
    const int cur = (t - t_lo) & 1;
    if (t + 1 < t_hi) STAGE(cur ^ 1, t + 1);

    if (t == 32) {   // phase switch: self keys use roped q
      const ushort_t* p0 = Qr + dsz(b * Sc + qrow0) * (NHc * HDc) + h * HDc;
      const ushort_t* p1 = Qr + dsz(b * Sc + qrow1) * (NHc * HDc) + h * HDc;
      #pragma unroll
      for (int c = 0; c < 4; ++c) {
        qf0[c] = *(const bf16x8*)&p0[c * 32 + fq * 8];
        qf1[c] = *(const bf16x8*)&p1[c * 32 + fq * 8];
      }
    }
    const bool self = (t >= 32);

    // shared fragments from LDS (swizzle undone at read)
    bf16x8 ka0[4], ka1[4], va[8];
    #pragma unroll
    for (int c = 0; c < 4; ++c) {
      const int ks = ((c * 4 + fq) ^ fr) * 8;
      ka0[c] = *(const bf16x8*)&sK[cur][kperm * 128 + ks];
      ka1[c] = *(const bf16x8*)&sK[cur][(kperm + 4) * 128 + ks];
    }
    #pragma unroll
    for (int dt = 0; dt < 8; ++dt)
      va[dt] = *(const bf16x8*)&sV[cur][(dt * 16 + fr) * 32 + vslot];

    // ---- subgroup 0 ----
    {
      f32x4 s0 = (f32x4){0.f, 0.f, 0.f, 0.f};
      f32x4 s1 = (f32x4){0.f, 0.f, 0.f, 0.f};
      #pragma unroll
      for (int c = 0; c < 4; ++c)
        s0 = __builtin_amdgcn_mfma_f32_16x16x32_bf16(ka0[c], qf0[c], s0, 0, 0, 0);
      #pragma unroll
      for (int c = 0; c < 4; ++c)
        s1 = __builtin_amdgcn_mfma_f32_16x16x32_bf16(ka1[c], qf0[c], s1, 0, 0, 0);
      if (self) {
        #pragma unroll
        for (int j = 0; j < 4; ++j) {
          s0[j] = (t * 32 + fq * 8 + j     - 1024 > qrow0) ? -1e30f : s0[j];
          s1[j] = (t * 32 + fq * 8 + 4 + j - 1024 > qrow0) ? -1e30f : s1[j];
        }
      }
      float tmax = fmaxf(fmaxf(fmaxf(s0[0], s0[1]), fmaxf(s0[2], s0[3])),
                         fmaxf(fmaxf(s1[0], s1[1]), fmaxf(s1[2], s1[3])));
      tmax = fmaxf(tmax, __shfl_xor(tmax, 16));
      tmax = fmaxf(tmax, __shfl_xor(tmax, 32));
      if (__any(tmax > m0 + 8.f)) {
        float mnew = fmaxf(m0, tmax);
        float corr = exp2f(m0 - mnew);
        l0 *= corr;
        #pragma unroll
        for (int dt = 0; dt < 8; ++dt) {
          ot0[dt][0] *= corr; ot0[dt][1] *= corr;
          ot0[dt][2] *= corr; ot0[dt][3] *= corr;
        }
        m0 = mnew;
      }
      float ps = 0.f;
      bf16x8 pb;
      #pragma unroll
      for (int j = 0; j < 4; ++j) { float p = exp2f(s0[j] - m0); ps += p; pb[j] = (__bf16)p; }
      #pragma unroll
      for (int j = 0; j < 4; ++j) { float p = exp2f(s1[j] - m0); ps += p; pb[j + 4] = (__bf16)p; }
      l0 += ps;
      #pragma unroll
      for (int dt = 0; dt < 8; ++dt)
        ot0[dt] = __builtin_amdgcn_mfma_f32_16x16x32_bf16(va[dt], pb, ot0[dt], 0, 0, 0);
    }
    // ---- subgroup 1 ----
    {
      f32x4 s0 = (f32x4){0.f, 0.f, 0.f, 0.f};
      f32x4 s1 = (f32x4){0.f, 0.f, 0.f, 0.f};
      #pragma unroll
      for (int c = 0; c < 4; ++c)
        s0 = __builtin_amdgcn_mfma_f32_16x16x32_bf16(ka0[c], qf1[c], s0, 0, 0, 0);
      #pragma unroll
      for (int c = 0; c < 4; ++c)
        s1 = __builtin_amdgcn_mfma_f32_16x16x32_bf16(ka1[c], qf1[c], s1, 0, 0, 0);
      if (self) {
        #pragma unroll
        for (int j = 0; j < 4; ++j) {
          s0[j] = (t * 32 + fq * 8 + j     - 1024 > qrow1) ? -1e30f : s0[j];
          s1[j] = (t * 32 + fq * 8 + 4 + j - 1024 > qrow1) ? -1e30f : s1[j];
        }
      }
      float tmax = fmaxf(fmaxf(fmaxf(s0[0], s0[1]), fmaxf(s0[2], s0[3])),
                         fmaxf(fmaxf(s1[0], s1[1]), fmaxf(s1[2], s1[3])));
      tmax = fmaxf(tmax, __shfl_xor(tmax, 16));
      tmax = fmaxf(tmax, __shfl_xor(tmax, 32));
      if (__any(tmax > m1 + 8.f)) {
        float mnew = fmaxf(m1, tmax);
        float corr = exp2f(m1 - mnew);
        l1 *= corr;
        #pragma unroll
        for (int dt = 0; dt < 8; ++dt) {
          ot1[dt][0] *= corr; ot1[dt][1] *= corr;
          ot1[dt][2] *= corr; ot1[dt][3] *= corr;
        }
        m1 = mnew;
      }
      float ps = 0.f;
      bf16x8 pb;
      #pragma unroll
      for (int j = 0; j < 4; ++j) { float p = exp2f(s0[j] - m1); ps += p; pb[j] = (__bf16)p; }
      #pragma unroll
      for (int j = 0; j < 4; ++j) { float p = exp2f(s1[j] - m1); ps += p; pb[j + 4] = (__bf16)p; }
      l1 += ps;
      #pragma unroll
      for (int dt = 0; dt < 8; ++dt)
        ot1[dt] = __builtin_amdgcn_mfma_f32_16x16x32_bf16(va[dt], pb, ot1[dt], 0, 0, 0);
    }

    __syncthreads();   // drains staging loads; safe buffer swap
  }
#undef STAGE

  l0 += __shfl_xor(l0, 16); l0 += __shfl_xor(l0, 32);
  l1 += __shfl_xor(l1, 16); l1 += __shfl_xor(l1, 32);

  // write partials (O unnormalized bf16; m,l f32)
  const int qin0 = w * 32 + fr;              // 0..127
  const int qin1 = qin0 + 16;
  ushort_t* ob0 = Opart + (dsz(third * 256 + blk) * 128 + qin0) * 128;
  ushort_t* ob1 = Opart + (dsz(third * 256 + blk) * 128 + qin1) * 128;
  #pragma unroll
  for (int dt = 0; dt < 8; ++dt) {
    ushort_t o4a[4];
    #pragma unroll
    for (int j = 0; j < 4; ++j) o4a[j] = f2bf(ot0[dt][j]);
    *(ushort4*)&ob0[dt * 16 + fq * 4] = *(ushort4*)o4a;
    #pragma unroll
    for (int j = 0; j < 4; ++j) o4a[j] = f2bf(ot1[dt][j]);
    *(ushort4*)&ob1[dt * 16 + fq * 4] = *(ushort4*)o4a;
  }
  if (fq == 0) {
    float* mlp0 = mlpart + (dsz(third * 256 + blk) * 128 + qin0) * 2;
    float* mlp1 = mlpart + (dsz(third * 256 + blk) * 128 + qin1) * 2;
    mlp0[0] = m0; mlp0[1] = l0;
    mlp1[0] = m1; mlp1[1] = l1;
  }
}

// ---------------------------------------------------------------------------
// Merge the 3 KV-split partials -> attnb bf16.
// ---------------------------------------------------------------------------
__global__ void attn_merge(const ushort_t* __restrict__ Opart,
                           const float* __restrict__ mlpart,
                           ushort_t* __restrict__ attnb)
{
  const int i = blockIdx.x * 256 + threadIdx.x;    // 8-elem group index
  const int e = i * 8;
  const int qg = e >> 7;          // (blk256, qin): 0..32767
  const int d0 = e & 127;
  const int blk = qg >> 7;        // 0..255
  const int qin = qg & 127;
  const int qt = blk & 7;
  const int h  = (blk >> 3) & 15;
  const int b  = blk >> 7;

  float mm[3], ll[3];
  #pragma unroll
  for (int p = 0; p < 3; ++p) {
    const float* ml = mlpart + (dsz(p * 256 + blk) * 128 + qin) * 2;
    mm[p] = ml[0]; ll[p] = ml[1];
  }
  float M = fmaxf(fmaxf(mm[0], mm[1]), mm[2]);
  float sc[3], L = 0.f;
  #pragma unroll
  for (int p = 0; p < 3; ++p) { sc[p] = exp2f(mm[p] - M); L += ll[p] * sc[p]; }
  const float Linv = 1.f / L;
  #pragma unroll
  for (int p = 0; p < 3; ++p) sc[p] *= Linv;

  float acc[8];
  #pragma unroll
  for (int j = 0; j < 8; ++j) acc[j] = 0.f;
  #pragma unroll
  for (int p = 0; p < 3; ++p) {
    const ushort_t* o = Opart + (dsz(p * 256 + blk) * 128 + qin) * 128 + d0;
    ushort4 a0 = *(const ushort4*)&o[0];
    ushort4 a1 = *(const ushort4*)&o[4];
    acc[0] += bf2f(a0.x) * sc[p]; acc[1] += bf2f(a0.y) * sc[p];
    acc[2] += bf2f(a0.z) * sc[p]; acc[3] += bf2f(a0.w) * sc[p];
    acc[4] += bf2f(a1.x) * sc[p]; acc[5] += bf2f(a1.y) * sc[p];
    acc[6] += bf2f(a1.z) * sc[p]; acc[7] += bf2f(a1.w) * sc[p];
  }

  ushort_t r[8];
  #pragma unroll
  for (int j = 0; j < 8; ++j) r[j] = f2bf(acc[j]);
  ushort_t* dst = attnb + dsz(b * Sc + qt * 128 + qin) * (NHc * HDc) + h * HDc + d0;
  *(ushort4*)&dst[0] = *(ushort4*)&r[0];
  *(ushort4*)&dst[4] = *(ushort4*)&r[4];
}

// ---------------------------------------------------------------------------
// Launch
// ---------------------------------------------------------------------------
extern "C" void kernel_launch(void* const* d_in, const int* in_sizes, int n_in,
                              void* d_out, int out_size, void* d_ws, size_t ws_size,
                              hipStream_t stream)
{
  const float* x    = (const float*)d_in[0];
  const int*   pos  = (const int*)d_in[2];
  const float* kbk  = (const float*)d_in[3];
  const float* kbv  = (const float*)d_in[4];
  const float* Wq   = (const float*)d_in[5];
  const float* Wqn  = (const float*)d_in[6];
  const float* Wk   = (const float*)d_in[7];
  const float* Wv   = (const float*)d_in[8];
  const float* Wo   = (const float*)d_in[9];
  float* out = (float*)d_out;

  const int MR = Bc * Sc;              // 2048
  const size_t MU = 1048576;

  ushort_t* U = (ushort_t*)d_ws;
  ushort_t* xb    = U;                 // 4M u
  ushort_t* Wqb   = U + 4  * MU;       // 4M
  ushort_t* Wqnb  = U + 8  * MU;       // 4M
  ushort_t* Wkb   = U + 12 * MU;       // 1M
  ushort_t* Wvb   = U + 13 * MU;       // 1M
  ushort_t* Wob   = U + 14 * MU;       // 4M
  ushort_t* qb    = U + 18 * MU;       // 4M (roped in-place -> Qr)
  ushort_t* qnb   = U + 22 * MU;       // 4M (pre-scaled)
  ushort_t* kkvb  = U + 26 * MU;       // 1M
  ushort_t* vkvb  = U + 27 * MU;       // 1M
  ushort_t* Kcat  = U + 28 * MU;       // 2M
  ushort_t* Vt    = U + 30 * MU;       // 2M
  ushort_t* attnb = U + 32 * MU;       // 4M  -> total 36M u = 72 MB
  // aliases (regions dead at the time they're written):
  ushort_t* Opart  = U;                        // exactly 12M u (xb..Wqnb, dead after gemm_proj)
  float*    mlpart = (float*)(U + 26 * MU);    // 786KB (kkvb, dead after rope_k_kcat)
  float2*   ropet  = (float2*)(U + 12 * MU);   // 1MB (Wkb, dead after gemm_proj; clobbered only by nothing <12.5MU... Opart ends at 12MU)

  dim3 blk(256);

  conv_all<<<18432, blk, 0, stream>>>(x, Wq, Wqn, Wk, Wv, Wo,
                                      xb, Wqb, Wqnb, Wkb, Wvb, Wob);
  gemm_proj<<<dim3(40, 16), blk, 0, stream>>>(xb, Wqb, Wqnb, Wkb, Wvb,
                                              qb, qnb, kkvb, vkvb);
  // rope table (overwrites Wkb region -- weights consumed by gemm_proj above)
  rope_tab<<<512, blk, 0, stream>>>(pos, ropet);
  rope_q_ip<<<8192, blk, 0, stream>>>(qb, ropet);
  kb_kcat<<<1024, blk, 0, stream>>>(kbk, Kcat);
  rope_k_kcat<<<2048, blk, 0, stream>>>(kkvb, ropet, Kcat);
  vt_build<<<dim3(64, 4, 8), blk, 0, stream>>>(kbv, vkvb, Vt);
  // attention: (b,h,qt) x third grid, 4 waves x 32q, KV-split partials
  attn_mfma7<<<dim3(256, 3), blk, 0, stream>>>(qb, qnb, Kcat, Vt, Opart, mlpart);
  attn_merge<<<2048, blk, 0, stream>>>(Opart, mlpart, attnb);
  gemm_bt_bf16<<<dim3(16, 16), blk, 0, stream>>>(attnb, Wob, out, MR, 2048, Hc);
}

// Round 11
// 203.727 us; speedup vs baseline: 1.6142x; 1.6142x over previous
//
#include <hip/hip_runtime.h>

// Problem constants
#define Bc   2
#define Sc   1024
#define Hc   2048
#define NHc  16
#define NKVc 4
#define HDc  128
#define KBc  1024
#define NREPc 4

typedef unsigned short ushort_t;
typedef unsigned int uint32;
typedef __attribute__((ext_vector_type(8))) __bf16 bf16x8;
typedef __attribute__((ext_vector_type(4))) float f32x4;

static __device__ __forceinline__ size_t dsz(int x) { return (size_t)x; }

static __device__ __forceinline__ ushort_t f2bf(float f) {
  uint32 u = __float_as_uint(f);
  u += 0x7fffu + ((u >> 16) & 1u);        // round-to-nearest-even
  return (ushort_t)(u >> 16);
}
static __device__ __forceinline__ float bf2f(ushort_t u) {
  return __uint_as_float(((uint32)u) << 16);
}

#define ROPE_INV 0.14391156831212787f   // ln(10000)/64
#define QSCALE   (0.08838834764831845f * 1.4426950408889634f)  // scale*log2e

// ---------------------------------------------------------------------------
// Fused fp32 -> bf16 conversion of all 6 inputs (one dispatch).
// ---------------------------------------------------------------------------
#define FSEG 1048576
__global__ void conv_all(const float* __restrict__ x,  const float* __restrict__ Wq,
                         const float* __restrict__ Wqn, const float* __restrict__ Wk,
                         const float* __restrict__ Wv,  const float* __restrict__ Wo,
                         ushort_t* xb, ushort_t* Wqb, ushort_t* Wqnb,
                         ushort_t* Wkb, ushort_t* Wvb, ushort_t* Wob)
{
  int i = blockIdx.x * 256 + threadIdx.x;      // f4 index, < 4.5*FSEG
  const float* s; ushort_t* d; int off;
  if      (i <     FSEG)            { s = x;   d = xb;   off = i; }
  else if (i < 2 * FSEG)            { s = Wq;  d = Wqb;  off = i - FSEG; }
  else if (i < 3 * FSEG)            { s = Wqn; d = Wqnb; off = i - 2 * FSEG; }
  else if (i < 3 * FSEG + FSEG / 4) { s = Wk;  d = Wkb;  off = i - 3 * FSEG; }
  else if (i < 3 * FSEG + FSEG / 2) { s = Wv;  d = Wvb;  off = i - 3 * FSEG - FSEG / 4; }
  else                              { s = Wo;  d = Wob;  off = i - 3 * FSEG - FSEG / 2; }
  float4 v = ((const float4*)s)[off];
  ushort4 o;
  o.x = f2bf(v.x); o.y = f2bf(v.y); o.z = f2bf(v.z); o.w = f2bf(v.w);
  ((ushort4*)d)[off] = o;
}

// ---------------------------------------------------------------------------
// global_load_lds helper
// ---------------------------------------------------------------------------
#define GL16(gsrc, ldst)                                                \
  __builtin_amdgcn_global_load_lds(                                     \
      (const __attribute__((address_space(1))) void*)(gsrc),            \
      (__attribute__((address_space(3))) void*)(ldst), 16, 0, 0)

// ---------------------------------------------------------------------------
// Fused projection GEMM (one dispatch, 640 blocks): C = xb * W^T for
// {Wq->qb, Wqn->qnb(*QSCALE), Wk->kkvb, Wv->vkvb}, bf16 outputs.
// ---------------------------------------------------------------------------
__global__ __launch_bounds__(256) void gemm_proj(
    const ushort_t* __restrict__ A,    // xb [2048][2048]
    const ushort_t* __restrict__ Wqb,  const ushort_t* __restrict__ Wqnb,
    const ushort_t* __restrict__ Wkb,  const ushort_t* __restrict__ Wvb,
    ushort_t* __restrict__ qb, ushort_t* __restrict__ qnb,
    ushort_t* __restrict__ kkvb, ushort_t* __restrict__ vkvb)
{
  __shared__ ushort_t sA[128 * 32];
  __shared__ ushort_t sB[128 * 32];

  const int K = Hc;                    // 2048
  const int bx = blockIdx.x;
  const ushort_t* Bseg; ushort_t* Cseg; int segN, colseg; float scale;
  if      (bx < 16) { Bseg = Wqb;  Cseg = qb;   segN = 2048; colseg = bx * 128;        scale = 1.f; }
  else if (bx < 32) { Bseg = Wqnb; Cseg = qnb;  segN = 2048; colseg = (bx - 16) * 128; scale = QSCALE; }
  else if (bx < 36) { Bseg = Wkb;  Cseg = kkvb; segN = 512;  colseg = (bx - 32) * 128; scale = 1.f; }
  else              { Bseg = Wvb;  Cseg = vkvb; segN = 512;  colseg = (bx - 36) * 128; scale = 1.f; }

  const int tid  = threadIdx.x;
  const int lane = tid & 63;
  const int wid  = tid >> 6;
  const int wr   = wid >> 1;
  const int wc   = wid & 1;
  const int row0 = blockIdx.y * 128;
  const int fr = lane & 15;
  const int fq = lane >> 4;

  f32x4 acc[4][4];
  #pragma unroll
  for (int m = 0; m < 4; ++m)
    #pragma unroll
    for (int n = 0; n < 4; ++n) acc[m][n] = (f32x4){0.f, 0.f, 0.f, 0.f};

  const int rS = tid >> 2;
  const int kg = (tid & 3) * 8;
  const ushort_t* Asrc0 = A + dsz(row0 + rS) * K + kg;
  const ushort_t* Asrc1 = A + dsz(row0 + 64 + rS) * K + kg;
  const ushort_t* Bsrc0 = Bseg + dsz(colseg + rS) * K + kg;
  const ushort_t* Bsrc1 = Bseg + dsz(colseg + 64 + rS) * K + kg;
  char* ldsA0 = (char*)sA + tid * 16;
  char* ldsA1 = (char*)sA + 4096 + tid * 16;
  char* ldsB0 = (char*)sB + tid * 16;
  char* ldsB1 = (char*)sB + 4096 + tid * 16;

  for (int k0 = 0; k0 < K; k0 += 32) {
    GL16(Asrc0 + k0, ldsA0);
    GL16(Asrc1 + k0, ldsA1);
    GL16(Bsrc0 + k0, ldsB0);
    GL16(Bsrc1 + k0, ldsB1);
    __syncthreads();

    bf16x8 a[4], b[4];
    #pragma unroll
    for (int m = 0; m < 4; ++m)
      a[m] = *(const bf16x8*)&sA[(wr * 64 + m * 16 + fr) * 32 + fq * 8];
    #pragma unroll
    for (int n = 0; n < 4; ++n)
      b[n] = *(const bf16x8*)&sB[(wc * 64 + n * 16 + fr) * 32 + fq * 8];
    #pragma unroll
    for (int m = 0; m < 4; ++m)
      #pragma unroll
      for (int n = 0; n < 4; ++n)
        acc[m][n] = __builtin_amdgcn_mfma_f32_16x16x32_bf16(a[m], b[n], acc[m][n], 0, 0, 0);
    __syncthreads();
  }

  #pragma unroll
  for (int m = 0; m < 4; ++m)
    #pragma unroll
    for (int n = 0; n < 4; ++n)
      #pragma unroll
      for (int j = 0; j < 4; ++j)
        Cseg[dsz(row0 + wr * 64 + m * 16 + fq * 4 + j) * segN +
             colseg + wc * 64 + n * 16 + fr] = f2bf(acc[m][n][j] * scale);
}

// ---------------------------------------------------------------------------
// Split-K bf16 GEMM for the Wo projection: grid (16,16,2); z-half computes
// a K=1024 partial of C = A*B^T into Cpart[z] (f32). add_partials sums.
// ---------------------------------------------------------------------------
__global__ __launch_bounds__(256) void gemm_bt_splitk(
    const ushort_t* __restrict__ A, const ushort_t* __restrict__ B,
    float* __restrict__ P0, float* __restrict__ P1)
{
  __shared__ ushort_t sA[128 * 32];
  __shared__ ushort_t sB[128 * 32];

  const int K = Hc;
  const int tid  = threadIdx.x;
  const int lane = tid & 63;
  const int wid  = tid >> 6;
  const int wr   = wid >> 1;
  const int wc   = wid & 1;
  const int row0 = blockIdx.y * 128;
  const int col0 = blockIdx.x * 128;
  const int koff = blockIdx.z * 1024;
  float* C = blockIdx.z ? P1 : P0;
  const int fr = lane & 15;
  const int fq = lane >> 4;

  f32x4 acc[4][4];
  #pragma unroll
  for (int m = 0; m < 4; ++m)
    #pragma unroll
    for (int n = 0; n < 4; ++n) acc[m][n] = (f32x4){0.f, 0.f, 0.f, 0.f};

  const int rS = tid >> 2;
  const int kg = (tid & 3) * 8;
  const ushort_t* Asrc0 = A + dsz(row0 + rS) * K + koff + kg;
  const ushort_t* Asrc1 = A + dsz(row0 + 64 + rS) * K + koff + kg;
  const ushort_t* Bsrc0 = B + dsz(col0 + rS) * K + koff + kg;
  const ushort_t* Bsrc1 = B + dsz(col0 + 64 + rS) * K + koff + kg;
  char* ldsA0 = (char*)sA + tid * 16;
  char* ldsA1 = (char*)sA + 4096 + tid * 16;
  char* ldsB0 = (char*)sB + tid * 16;
  char* ldsB1 = (char*)sB + 4096 + tid * 16;

  for (int k0 = 0; k0 < 1024; k0 += 32) {
    GL16(Asrc0 + k0, ldsA0);
    GL16(Asrc1 + k0, ldsA1);
    GL16(Bsrc0 + k0, ldsB0);
    GL16(Bsrc1 + k0, ldsB1);
    __syncthreads();

    bf16x8 a[4], b[4];
    #pragma unroll
    for (int m = 0; m < 4; ++m)
      a[m] = *(const bf16x8*)&sA[(wr * 64 + m * 16 + fr) * 32 + fq * 8];
    #pragma unroll
    for (int n = 0; n < 4; ++n)
      b[n] = *(const bf16x8*)&sB[(wc * 64 + n * 16 + fr) * 32 + fq * 8];
    #pragma unroll
    for (int m = 0; m < 4; ++m)
      #pragma unroll
      for (int n = 0; n < 4; ++n)
        acc[m][n] = __builtin_amdgcn_mfma_f32_16x16x32_bf16(a[m], b[n], acc[m][n], 0, 0, 0);
    __syncthreads();
  }

  #pragma unroll
  for (int m = 0; m < 4; ++m)
    #pragma unroll
    for (int n = 0; n < 4; ++n)
      #pragma unroll
      for (int j = 0; j < 4; ++j)
        C[dsz(row0 + wr * 64 + m * 16 + fq * 4 + j) * 2048 +
          col0 + wc * 64 + n * 16 + fr] = acc[m][n][j];
}

__global__ void add_partials(const float* __restrict__ P0, const float* __restrict__ P1,
                             float* __restrict__ out)
{
  int i = blockIdx.x * 256 + threadIdx.x;      // float4 index, 1M total
  float4 a = ((const float4*)P0)[i];
  float4 b = ((const float4*)P1)[i];
  float4 r; r.x = a.x + b.x; r.y = a.y + b.y; r.z = a.z + b.z; r.w = a.w + b.w;
  ((float4*)out)[i] = r;
}

// ---------------------------------------------------------------------------
// RoPE cos/sin table: tab[r][j] = (cos, sin) of pos[r] * invfreq[j].
// ---------------------------------------------------------------------------
__global__ void rope_tab(const int* __restrict__ pos, float2* __restrict__ tab)
{
  int idx = blockIdx.x * 256 + threadIdx.x;   // 131072
  int j = idx & 63;
  int r = idx >> 6;
  float p = (float)pos[r];
  float f = p * expf(-(float)j * ROPE_INV);
  float2 cs; cs.x = cosf(f); cs.y = sinf(f);
  tab[idx] = cs;
}

// RoPE in-place on bf16 qb, folds in QSCALE (table-driven).
__global__ void rope_q_ip(ushort_t* __restrict__ qb, const float2* __restrict__ tab)
{
  int idx = blockIdx.x * blockDim.x + threadIdx.x;   // 2M
  int j = idx & 63;
  int h = (idx >> 6) & 15;
  int r = idx >> 10;
  float2 cs = tab[r * 64 + j];
  ushort_t* d = qb + dsz(r) * (NHc * HDc) + h * HDc;
  float x1 = bf2f(d[j]), x2 = bf2f(d[j + 64]);
  d[j]      = f2bf((x1 * cs.x - x2 * cs.y) * QSCALE);
  d[j + 64] = f2bf((x2 * cs.x + x1 * cs.y) * QSCALE);
}

// RoPE self-k (bf16 in) -> Kcat rows 1024..2047 (table-driven)
__global__ void rope_k_kcat(const ushort_t* __restrict__ kkvb, const float2* __restrict__ tab,
                            ushort_t* __restrict__ Kcat)
{
  int idx = blockIdx.x * blockDim.x + threadIdx.x;   // 512K
  int j = idx & 63;
  int kvh = (idx >> 6) & 3;
  int s = (idx >> 8) & 1023;
  int b = idx >> 18;
  float2 cs = tab[(b * Sc + s) * 64 + j];
  const ushort_t* src = kkvb + dsz(b * Sc + s) * (NKVc * HDc) + kvh * HDc;
  ushort_t* dst = Kcat + (dsz(b * NKVc + kvh) * 2048 + 1024 + s) * HDc;
  float x1 = bf2f(src[j]), x2 = bf2f(src[j + 64]);
  dst[j]      = f2bf(x1 * cs.x - x2 * cs.y);
  dst[j + 64] = f2bf(x2 * cs.x + x1 * cs.y);
}

// kb_keys fp32 -> Kcat rows 0..1023 bf16
__global__ void kb_kcat(const float* __restrict__ src, ushort_t* __restrict__ Kcat)
{
  int i = blockIdx.x * blockDim.x + threadIdx.x;     // 262144
  int d4 = i & 31;
  int kvh = (i >> 5) & 3;
  int k = (i >> 7) & 1023;
  int b = i >> 17;
  float4 v = *(const float4*)&src[dsz(b * KBc + k) * (NKVc * HDc) + kvh * HDc + d4 * 4];
  ushort4 o;
  o.x = f2bf(v.x); o.y = f2bf(v.y); o.z = f2bf(v.z); o.w = f2bf(v.w);
  *(ushort4*)&Kcat[(dsz(b * NKVc + kvh) * 2048 + k) * HDc + d4 * 4] = o;
}

// Build Vt[b][kvh][128][2048] from kb_values (f32) + vkvb (bf16)
__global__ __launch_bounds__(256) void vt_build(const float* __restrict__ kbv,
                                                const ushort_t* __restrict__ vkvb,
                                                ushort_t* __restrict__ Vt)
{
  __shared__ float sT[32][33];
  const int k0 = blockIdx.x * 32;
  const int d0 = blockIdx.y * 32;
  const int bk = blockIdx.z;
  const int b = bk >> 2, kvh = bk & 3;
  const int tid = threadIdx.x;

  #pragma unroll
  for (int t = 0; t < 4; ++t) {
    int li = tid + t * 256;
    int kk = li >> 5, dl = li & 31;
    int kg = k0 + kk;
    float v = (kg < 1024)
      ? kbv[dsz(b * KBc + kg) * (NKVc * HDc) + kvh * HDc + d0 + dl]
      : bf2f(vkvb[dsz(b * Sc + kg - 1024) * (NKVc * HDc) + kvh * HDc + d0 + dl]);
    sT[kk][dl] = v;
  }
  __syncthreads();
  #pragma unroll
  for (int t = 0; t < 4; ++t) {
    int li = tid + t * 256;
    int dl = li >> 5, kk = li & 31;
    Vt[(dsz(b * NKVc + kvh) * HDc + d0 + dl) * 2048 + k0 + kk] = f2bf(sT[kk][dl]);
  }
}

// ---------------------------------------------------------------------------
// Attention v7b: identical structure to R10's v7 (4 waves x 32q, 2 subgroups,
// 3-way KV split) but __launch_bounds__(256, 2): the (256,3) variant capped
// the unified register file at ~170 and spilled (WRITE_SIZE 129MB). No cap.
// ---------------------------------------------------------------------------
__global__ __launch_bounds__(256, 2) void attn_mfma7(
    const ushort_t* __restrict__ Qr,   // roped q (pre-scaled), (B*S, 2048)
    const ushort_t* __restrict__ Qn,   // q_new (pre-scaled), (B*S, 2048)
    const ushort_t* __restrict__ Kcat, // (B, NKV, 2048, 128)
    const ushort_t* __restrict__ Vt,   // (B, NKV, 128, 2048)
    ushort_t* __restrict__ Opart,      // [3][256][128][128] bf16
    float* __restrict__ mlpart)        // [3][256][128][2]
{
  __shared__ ushort_t sK[2][32 * 128];   // 8KB/buf, rows XOR-swizzled
  __shared__ ushort_t sV[2][128 * 32];   // 8KB/buf, slots XOR-swizzled

  const int tid = threadIdx.x;
  const int lane = tid & 63;
  const int w = tid >> 6;                // 0..3
  const int fr = lane & 15;
  const int fq = lane >> 4;
  const int blk = blockIdx.x;            // (b,h,qt): qt 0..7
  const int third = blockIdx.y;          // 0..2
  const int qt = blk & 7;
  const int h  = (blk >> 3) & 15;
  const int b  = blk >> 7;
  const int kvh = h >> 2;
  const int qrow0 = qt * 128 + w * 32 + fr;   // subgroup 0
  const int qrow1 = qrow0 + 16;               // subgroup 1
  const int kperm = ((fr >> 2) << 3) + (fr & 3);   // u(kperm) = fr

  const ushort_t* Kb = Kcat + dsz(b * NKVc + kvh) * 2048 * HDc;
  const ushort_t* Vb = Vt   + dsz(b * NKVc + kvh) * HDc * 2048;

  const int nt  = 36 + 4 * qt;           // key tiles (keys = 1024 + (qt+1)*128)
  const int q3 = nt / 3, r3 = nt % 3;
  const int t_lo = third * q3 + (third < r3 ? third : r3);
  const int t_hi = t_lo + q3 + (third < r3 ? 1 : 0);

  // staging offsets (R6-verified, conflict-free): 256 threads, 2 GL16 each
  const int kr0 = tid >> 4;
  const int ks0 = tid & 15;
  const int ku0 = (kr0 & 3) | ((kr0 >> 3) << 2);
  const int kOffA = kr0 * 256 + ((ks0 ^ ku0) * 16);
  const int kOffB = (kr0 + 16) * 256 + ((ks0 ^ (ku0 + 8)) * 16);
  const int vr0 = tid >> 2;
  const int vs0 = tid & 3;
  const int vu0 = (vr0 >> 1) & 3;
  const size_t vOffA = (size_t)vr0 * 4096 + ((vs0 ^ vu0) * 16);
  const size_t vOffB = vOffA + (size_t)64 * 4096;

  const int vslot = (fq ^ ((fr >> 1) & 3)) * 8;

#define STAGE(bi, t)                                                   \
  {                                                                    \
    const char* kgb = (const char*)Kb + (size_t)(t) * 8192;            \
    const char* vgb = (const char*)Vb + (size_t)(t) * 64;              \
    GL16(kgb + kOffA, (char*)&sK[bi][0] + tid * 16);                   \
    GL16(kgb + kOffB, (char*)&sK[bi][0] + 4096 + tid * 16);            \
    GL16(vgb + vOffA, (char*)&sV[bi][0] + tid * 16);                   \
    GL16(vgb + vOffB, (char*)&sV[bi][0] + 4096 + tid * 16);            \
  }

  // Q fragments for the starting phase (both subgroups)
  bf16x8 qf0[4], qf1[4];
  {
    const ushort_t* base = (t_lo >= 32 ? Qr : Qn);
    const ushort_t* p0 = base + dsz(b * Sc + qrow0) * (NHc * HDc) + h * HDc;
    const ushort_t* p1 = base + dsz(b * Sc + qrow1) * (NHc * HDc) + h * HDc;
    #pragma unroll
    for (int c = 0; c < 4; ++c) {
      qf0[c] = *(const bf16x8*)&p0[c * 32 + fq * 8];
      qf1[c] = *(const bf16x8*)&p1[c * 32 + fq * 8];
    }
  }

  float m0 = -1e30f, l0 = 0.f, m1 = -1e30f, l1 = 0.f;
  f32x4 ot0[8], ot1[8];
  #pragma unroll
  for (int dt = 0; dt < 8; ++dt) {
    ot0[dt] = (f32x4){0.f, 0.f, 0.f, 0.f};
    ot1[dt] = (f32x4){0.f, 0.f, 0.f, 0.f};
  }

  STAGE(0, t_lo);
  __syncthreads();

  for (int t = t_lo; t < t_hi; ++t) {
    const int cur = (t - t_lo) & 1;
    if (t + 1 < t_hi) STAGE(cur ^ 1, t + 1);

    if (t == 32) {   // phase switch: self keys use roped q
      const ushort_t* p0 = Qr + dsz(b * Sc + qrow0) * (NHc * HDc) + h * HDc;
      const ushort_t* p1 = Qr + dsz(b * Sc + qrow1) * (NHc * HDc) + h * HDc;
      #pragma unroll
      for (int c = 0; c < 4; ++c) {
        qf0[c] = *(const bf16x8*)&p0[c * 32 + fq * 8];
        qf1[c] = *(const bf16x8*)&p1[c * 32 + fq * 8];
      }
    }
    const bool self = (t >= 32);

    // shared fragments from LDS (swizzle undone at read)
    bf16x8 ka0[4], ka1[4], va[8];
    #pragma unroll
    for (int c = 0; c < 4; ++c) {
      const int ks = ((c * 4 + fq) ^ fr) * 8;
      ka0[c] = *(const bf16x8*)&sK[cur][kperm * 128 + ks];
      ka1[c] = *(const bf16x8*)&sK[cur][(kperm + 4) * 128 + ks];
    }
    #pragma unroll
    for (int dt = 0; dt < 8; ++dt)
      va[dt] = *(const bf16x8*)&sV[cur][(dt * 16 + fr) * 32 + vslot];

    // ---- subgroup 0 ----
    {
      f32x4 s0 = (f32x4){0.f, 0.f, 0.f, 0.f};
      f32x4 s1 = (f32x4){0.f, 0.f, 0.f, 0.f};
      #pragma unroll
      for (int c = 0; c < 4; ++c)
        s0 = __builtin_amdgcn_mfma_f32_16x16x32_bf16(ka0[c], qf0[c], s0, 0, 0, 0);
      #pragma unroll
      for (int c = 0; c < 4; ++c)
        s1 = __builtin_amdgcn_mfma_f32_16x16x32_bf16(ka1[c], qf0[c], s1, 0, 0, 0);
      if (self) {
        #pragma unroll
        for (int j = 0; j < 4; ++j) {
          s0[j] = (t * 32 + fq * 8 + j     - 1024 > qrow0) ? -1e30f : s0[j];
          s1[j] = (t * 32 + fq * 8 + 4 + j - 1024 > qrow0) ? -1e30f : s1[j];
        }
      }
      float tmax = fmaxf(fmaxf(fmaxf(s0[0], s0[1]), fmaxf(s0[2], s0[3])),
                         fmaxf(fmaxf(s1[0], s1[1]), fmaxf(s1[2], s1[3])));
      tmax = fmaxf(tmax, __shfl_xor(tmax, 16));
      tmax = fmaxf(tmax, __shfl_xor(tmax, 32));
      if (__any(tmax > m0 + 8.f)) {
        float mnew = fmaxf(m0, tmax);
        float corr = exp2f(m0 - mnew);
        l0 *= corr;
        #pragma unroll
        for (int dt = 0; dt < 8; ++dt) {
          ot0[dt][0] *= corr; ot0[dt][1] *= corr;
          ot0[dt][2] *= corr; ot0[dt][3] *= corr;
        }
        m0 = mnew;
      }
      float ps = 0.f;
      bf16x8 pb;
      #pragma unroll
      for (int j = 0; j < 4; ++j) { float p = exp2f(s0[j] - m0); ps += p; pb[j] = (__bf16)p; }
      #pragma unroll
      for (int j = 0; j < 4; ++j) { float p = exp2f(s1[j] - m0); ps += p; pb[j + 4] = (__bf16)p; }
      l0 += ps;
      #pragma unroll
      for (int dt = 0; dt < 8; ++dt)
        ot0[dt] = __builtin_amdgcn_mfma_f32_16x16x32_bf16(va[dt], pb, ot0[dt], 0, 0, 0);
    }
    // ---- subgroup 1 ----
    {
      f32x4 s0 = (f32x4){0.f, 0.f, 0.f, 0.f};
      f32x4 s1 = (f32x4){0.f, 0.f, 0.f, 0.f};
      #pragma unroll
      for (int c = 0; c < 4; ++c)
        s0 = __builtin_amdgcn_mfma_f32_16x16x32_bf16(ka0[c], qf1[c], s0, 0, 0, 0);
      #pragma unroll
      for (int c = 0; c < 4; ++c)
        s1 = __builtin_amdgcn_mfma_f32_16x16x32_bf16(ka1[c], qf1[c], s1, 0, 0, 0);
      if (self) {
        #pragma unroll
        for (int j = 0; j < 4; ++j) {
          s0[j] = (t * 32 + fq * 8 + j     - 1024 > qrow1) ? -1e30f : s0[j];
          s1[j] = (t * 32 + fq * 8 + 4 + j - 1024 > qrow1) ? -1e30f : s1[j];
        }
      }
      float tmax = fmaxf(fmaxf(fmaxf(s0[0], s0[1]), fmaxf(s0[2], s0[3])),
                         fmaxf(fmaxf(s1[0], s1[1]), fmaxf(s1[2], s1[3])));
      tmax = fmaxf(tmax, __shfl_xor(tmax, 16));
      tmax = fmaxf(tmax, __shfl_xor(tmax, 32));
      if (__any(tmax > m1 + 8.f)) {
        float mnew = fmaxf(m1, tmax);
        float corr = exp2f(m1 - mnew);
        l1 *= corr;
        #pragma unroll
        for (int dt = 0; dt < 8; ++dt) {
          ot1[dt][0] *= corr; ot1[dt][1] *= corr;
          ot1[dt][2] *= corr; ot1[dt][3] *= corr;
        }
        m1 = mnew;
      }
      float ps = 0.f;
      bf16x8 pb;
      #pragma unroll
      for (int j = 0; j < 4; ++j) { float p = exp2f(s0[j] - m1); ps += p; pb[j] = (__bf16)p; }
      #pragma unroll
      for (int j = 0; j < 4; ++j) { float p = exp2f(s1[j] - m1); ps += p; pb[j + 4] = (__bf16)p; }
      l1 += ps;
      #pragma unroll
      for (int dt = 0; dt < 8; ++dt)
        ot1[dt] = __builtin_amdgcn_mfma_f32_16x16x32_bf16(va[dt], pb, ot1[dt], 0, 0, 0);
    }

    __syncthreads();   // drains staging loads; safe buffer swap
  }
#undef STAGE

  l0 += __shfl_xor(l0, 16); l0 += __shfl_xor(l0, 32);
  l1 += __shfl_xor(l1, 16); l1 += __shfl_xor(l1, 32);

  // write partials (O unnormalized bf16; m,l f32)
  const int qin0 = w * 32 + fr;              // 0..127
  const int qin1 = qin0 + 16;
  ushort_t* ob0 = Opart + (dsz(third * 256 + blk) * 128 + qin0) * 128;
  ushort_t* ob1 = Opart + (dsz(third * 256 + blk) * 128 + qin1) * 128;
  #pragma unroll
  for (int dt = 0; dt < 8; ++dt) {
    ushort_t o4a[4];
    #pragma unroll
    for (int j = 0; j < 4; ++j) o4a[j] = f2bf(ot0[dt][j]);
    *(ushort4*)&ob0[dt * 16 + fq * 4] = *(ushort4*)o4a;
    #pragma unroll
    for (int j = 0; j < 4; ++j) o4a[j] = f2bf(ot1[dt][j]);
    *(ushort4*)&ob1[dt * 16 + fq * 4] = *(ushort4*)o4a;
  }
  if (fq == 0) {
    float* mlp0 = mlpart + (dsz(third * 256 + blk) * 128 + qin0) * 2;
    float* mlp1 = mlpart + (dsz(third * 256 + blk) * 128 + qin1) * 2;
    mlp0[0] = m0; mlp0[1] = l0;
    mlp1[0] = m1; mlp1[1] = l1;
  }
}

// ---------------------------------------------------------------------------
// Merge the 3 KV-split partials -> attnb bf16.
// ---------------------------------------------------------------------------
__global__ void attn_merge(const ushort_t* __restrict__ Opart,
                           const float* __restrict__ mlpart,
                           ushort_t* __restrict__ attnb)
{
  const int i = blockIdx.x * 256 + threadIdx.x;    // 8-elem group index
  const int e = i * 8;
  const int qg = e >> 7;          // (blk256, qin): 0..32767
  const int d0 = e & 127;
  const int blk = qg >> 7;        // 0..255
  const int qin = qg & 127;
  const int qt = blk & 7;
  const int h  = (blk >> 3) & 15;
  const int b  = blk >> 7;

  float mm[3], ll[3];
  #pragma unroll
  for (int p = 0; p < 3; ++p) {
    const float* ml = mlpart + (dsz(p * 256 + blk) * 128 + qin) * 2;
    mm[p] = ml[0]; ll[p] = ml[1];
  }
  float M = fmaxf(fmaxf(mm[0], mm[1]), mm[2]);
  float sc[3], L = 0.f;
  #pragma unroll
  for (int p = 0; p < 3; ++p) { sc[p] = exp2f(mm[p] - M); L += ll[p] * sc[p]; }
  const float Linv = 1.f / L;
  #pragma unroll
  for (int p = 0; p < 3; ++p) sc[p] *= Linv;

  float acc[8];
  #pragma unroll
  for (int j = 0; j < 8; ++j) acc[j] = 0.f;
  #pragma unroll
  for (int p = 0; p < 3; ++p) {
    const ushort_t* o = Opart + (dsz(p * 256 + blk) * 128 + qin) * 128 + d0;
    ushort4 a0 = *(const ushort4*)&o[0];
    ushort4 a1 = *(const ushort4*)&o[4];
    acc[0] += bf2f(a0.x) * sc[p]; acc[1] += bf2f(a0.y) * sc[p];
    acc[2] += bf2f(a0.z) * sc[p]; acc[3] += bf2f(a0.w) * sc[p];
    acc[4] += bf2f(a1.x) * sc[p]; acc[5] += bf2f(a1.y) * sc[p];
    acc[6] += bf2f(a1.z) * sc[p]; acc[7] += bf2f(a1.w) * sc[p];
  }

  ushort_t r[8];
  #pragma unroll
  for (int j = 0; j < 8; ++j) r[j] = f2bf(acc[j]);
  ushort_t* dst = attnb + dsz(b * Sc + qt * 128 + qin) * (NHc * HDc) + h * HDc + d0;
  *(ushort4*)&dst[0] = *(ushort4*)&r[0];
  *(ushort4*)&dst[4] = *(ushort4*)&r[4];
}

// ---------------------------------------------------------------------------
// Launch
// ---------------------------------------------------------------------------
extern "C" void kernel_launch(void* const* d_in, const int* in_sizes, int n_in,
                              void* d_out, int out_size, void* d_ws, size_t ws_size,
                              hipStream_t stream)
{
  const float* x    = (const float*)d_in[0];
  const int*   pos  = (const int*)d_in[2];
  const float* kbk  = (const float*)d_in[3];
  const float* kbv  = (const float*)d_in[4];
  const float* Wq   = (const float*)d_in[5];
  const float* Wqn  = (const float*)d_in[6];
  const float* Wk   = (const float*)d_in[7];
  const float* Wv   = (const float*)d_in[8];
  const float* Wo   = (const float*)d_in[9];
  float* out = (float*)d_out;

  const size_t MU = 1048576;

  ushort_t* U = (ushort_t*)d_ws;
  ushort_t* xb    = U;                 // 4M u
  ushort_t* Wqb   = U + 4  * MU;       // 4M
  ushort_t* Wqnb  = U + 8  * MU;       // 4M
  ushort_t* Wkb   = U + 12 * MU;       // 1M
  ushort_t* Wvb   = U + 13 * MU;       // 1M
  ushort_t* Wob   = U + 14 * MU;       // 4M
  ushort_t* qb    = U + 18 * MU;       // 4M (roped in-place -> Qr)
  ushort_t* qnb   = U + 22 * MU;       // 4M (pre-scaled)
  ushort_t* kkvb  = U + 26 * MU;       // 1M
  ushort_t* vkvb  = U + 27 * MU;       // 1M
  ushort_t* Kcat  = U + 28 * MU;       // 2M
  ushort_t* Vt    = U + 30 * MU;       // 2M
  ushort_t* attnb = U + 32 * MU;       // 4M  -> total 36M u = 72 MB
  // aliases (regions dead at the time they're written):
  ushort_t* Opart  = U;                        // 12M u (xb..Wqnb, dead after gemm_proj)
  float*    mlpart = (float*)(U + 26 * MU);    // 786KB (kkvb, dead after rope_k_kcat)
  float2*   ropet  = (float2*)(U + 12 * MU);   // 1MB (Wkb, dead after gemm_proj)
  // split-K partials for the Wo GEMM (dead regions at Wo-GEMM time):
  float*    P0     = (float*)U;                // 16MB (Opart dead after attn_merge)
  float*    P1     = (float*)(U + 18 * MU);    // 16MB (qb/qnb dead after attention)

  dim3 blk(256);

  conv_all<<<18432, blk, 0, stream>>>(x, Wq, Wqn, Wk, Wv, Wo,
                                      xb, Wqb, Wqnb, Wkb, Wvb, Wob);
  gemm_proj<<<dim3(40, 16), blk, 0, stream>>>(xb, Wqb, Wqnb, Wkb, Wvb,
                                              qb, qnb, kkvb, vkvb);
  rope_tab<<<512, blk, 0, stream>>>(pos, ropet);
  rope_q_ip<<<8192, blk, 0, stream>>>(qb, ropet);
  kb_kcat<<<1024, blk, 0, stream>>>(kbk, Kcat);
  rope_k_kcat<<<2048, blk, 0, stream>>>(kkvb, ropet, Kcat);
  vt_build<<<dim3(64, 4, 8), blk, 0, stream>>>(kbv, vkvb, Vt);
  // attention: (b,h,qt) x third grid, 4 waves x 32q, KV-split partials
  attn_mfma7<<<dim3(256, 3), blk, 0, stream>>>(qb, qnb, Kcat, Vt, Opart, mlpart);
  attn_merge<<<2048, blk, 0, stream>>>(Opart, mlpart, attnb);
  // Wo projection, 2-way split-K (512 blocks = 2/CU) + f32 add
  gemm_bt_splitk<<<dim3(16, 16, 2), blk, 0, stream>>>(attnb, Wob, P0, P1);
  add_partials<<<4096, blk, 0, stream>>>(P0, P1, out);
}

// Round 12
// 189.438 us; speedup vs baseline: 1.7360x; 1.0754x over previous
//
#include <hip/hip_runtime.h>

// Problem constants
#define Bc   2
#define Sc   1024
#define Hc   2048
#define NHc  16
#define NKVc 4
#define HDc  128
#define KBc  1024
#define NREPc 4

typedef unsigned short ushort_t;
typedef unsigned int uint32;
typedef __attribute__((ext_vector_type(8))) __bf16 bf16x8;
typedef __attribute__((ext_vector_type(4))) float f32x4;

static __device__ __forceinline__ size_t dsz(int x) { return (size_t)x; }

static __device__ __forceinline__ ushort_t f2bf(float f) {
  uint32 u = __float_as_uint(f);
  u += 0x7fffu + ((u >> 16) & 1u);        // round-to-nearest-even
  return (ushort_t)(u >> 16);
}
static __device__ __forceinline__ float bf2f(ushort_t u) {
  return __uint_as_float(((uint32)u) << 16);
}

#define ROPE_INV 0.14391156831212787f   // ln(10000)/64
#define QSCALE   (0.08838834764831845f * 1.4426950408889634f)  // scale*log2e

// ---------------------------------------------------------------------------
// Fused fp32 -> bf16 conversion of all 6 inputs (one dispatch).
// ---------------------------------------------------------------------------
#define FSEG 1048576
__global__ void conv_all(const float* __restrict__ x,  const float* __restrict__ Wq,
                         const float* __restrict__ Wqn, const float* __restrict__ Wk,
                         const float* __restrict__ Wv,  const float* __restrict__ Wo,
                         ushort_t* xb, ushort_t* Wqb, ushort_t* Wqnb,
                         ushort_t* Wkb, ushort_t* Wvb, ushort_t* Wob)
{
  int i = blockIdx.x * 256 + threadIdx.x;      // f4 index, < 4.5*FSEG
  const float* s; ushort_t* d; int off;
  if      (i <     FSEG)            { s = x;   d = xb;   off = i; }
  else if (i < 2 * FSEG)            { s = Wq;  d = Wqb;  off = i - FSEG; }
  else if (i < 3 * FSEG)            { s = Wqn; d = Wqnb; off = i - 2 * FSEG; }
  else if (i < 3 * FSEG + FSEG / 4) { s = Wk;  d = Wkb;  off = i - 3 * FSEG; }
  else if (i < 3 * FSEG + FSEG / 2) { s = Wv;  d = Wvb;  off = i - 3 * FSEG - FSEG / 4; }
  else                              { s = Wo;  d = Wob;  off = i - 3 * FSEG - FSEG / 2; }
  float4 v = ((const float4*)s)[off];
  ushort4 o;
  o.x = f2bf(v.x); o.y = f2bf(v.y); o.z = f2bf(v.z); o.w = f2bf(v.w);
  ((ushort4*)d)[off] = o;
}

// ---------------------------------------------------------------------------
// global_load_lds helper
// ---------------------------------------------------------------------------
#define GL16(gsrc, ldst)                                                \
  __builtin_amdgcn_global_load_lds(                                     \
      (const __attribute__((address_space(1))) void*)(gsrc),            \
      (__attribute__((address_space(3))) void*)(ldst), 16, 0, 0)

// ---------------------------------------------------------------------------
// Fused projection GEMM (one dispatch, 640 blocks, XCD-swizzled):
// C = xb * W^T for {Wq->qb, Wqn->qnb(*QSCALE), Wk->kkvb, Wv->vkvb}, bf16 out.
// ---------------------------------------------------------------------------
__global__ __launch_bounds__(256) void gemm_proj(
    const ushort_t* __restrict__ A,    // xb [2048][2048]
    const ushort_t* __restrict__ Wqb,  const ushort_t* __restrict__ Wqnb,
    const ushort_t* __restrict__ Wkb,  const ushort_t* __restrict__ Wvb,
    ushort_t* __restrict__ qb, ushort_t* __restrict__ qnb,
    ushort_t* __restrict__ kkvb, ushort_t* __restrict__ vkvb)
{
  __shared__ ushort_t sA[128 * 32];
  __shared__ ushort_t sB[128 * 32];

  // XCD-aware swizzle (T1): 640 blocks, 640%8==0 -> bijective.
  // Same-XCD consecutive blocks walk bx fastest -> share A-panel in L2.
  const int id = blockIdx.y * 40 + blockIdx.x;     // HW dispatch order (x fastest)
  const int sw = (id & 7) * 80 + (id >> 3);        // 0..639
  const int bx = sw % 40;
  const int by = sw / 40;

  const int K = Hc;                    // 2048
  const ushort_t* Bseg; ushort_t* Cseg; int segN, colseg; float scale;
  if      (bx < 16) { Bseg = Wqb;  Cseg = qb;   segN = 2048; colseg = bx * 128;        scale = 1.f; }
  else if (bx < 32) { Bseg = Wqnb; Cseg = qnb;  segN = 2048; colseg = (bx - 16) * 128; scale = QSCALE; }
  else if (bx < 36) { Bseg = Wkb;  Cseg = kkvb; segN = 512;  colseg = (bx - 32) * 128; scale = 1.f; }
  else              { Bseg = Wvb;  Cseg = vkvb; segN = 512;  colseg = (bx - 36) * 128; scale = 1.f; }

  const int tid  = threadIdx.x;
  const int lane = tid & 63;
  const int wid  = tid >> 6;
  const int wr   = wid >> 1;
  const int wc   = wid & 1;
  const int row0 = by * 128;
  const int fr = lane & 15;
  const int fq = lane >> 4;

  f32x4 acc[4][4];
  #pragma unroll
  for (int m = 0; m < 4; ++m)
    #pragma unroll
    for (int n = 0; n < 4; ++n) acc[m][n] = (f32x4){0.f, 0.f, 0.f, 0.f};

  const int rS = tid >> 2;
  const int kg = (tid & 3) * 8;
  const ushort_t* Asrc0 = A + dsz(row0 + rS) * K + kg;
  const ushort_t* Asrc1 = A + dsz(row0 + 64 + rS) * K + kg;
  const ushort_t* Bsrc0 = Bseg + dsz(colseg + rS) * K + kg;
  const ushort_t* Bsrc1 = Bseg + dsz(colseg + 64 + rS) * K + kg;
  char* ldsA0 = (char*)sA + tid * 16;
  char* ldsA1 = (char*)sA + 4096 + tid * 16;
  char* ldsB0 = (char*)sB + tid * 16;
  char* ldsB1 = (char*)sB + 4096 + tid * 16;

  for (int k0 = 0; k0 < K; k0 += 32) {
    GL16(Asrc0 + k0, ldsA0);
    GL16(Asrc1 + k0, ldsA1);
    GL16(Bsrc0 + k0, ldsB0);
    GL16(Bsrc1 + k0, ldsB1);
    __syncthreads();

    bf16x8 a[4], b[4];
    #pragma unroll
    for (int m = 0; m < 4; ++m)
      a[m] = *(const bf16x8*)&sA[(wr * 64 + m * 16 + fr) * 32 + fq * 8];
    #pragma unroll
    for (int n = 0; n < 4; ++n)
      b[n] = *(const bf16x8*)&sB[(wc * 64 + n * 16 + fr) * 32 + fq * 8];
    #pragma unroll
    for (int m = 0; m < 4; ++m)
      #pragma unroll
      for (int n = 0; n < 4; ++n)
        acc[m][n] = __builtin_amdgcn_mfma_f32_16x16x32_bf16(a[m], b[n], acc[m][n], 0, 0, 0);
    __syncthreads();
  }

  #pragma unroll
  for (int m = 0; m < 4; ++m)
    #pragma unroll
    for (int n = 0; n < 4; ++n)
      #pragma unroll
      for (int j = 0; j < 4; ++j)
        Cseg[dsz(row0 + wr * 64 + m * 16 + fq * 4 + j) * segN +
             colseg + wc * 64 + n * 16 + fr] = f2bf(acc[m][n][j] * scale);
}

// ---------------------------------------------------------------------------
// Split-K bf16 GEMM for the Wo projection: grid (16,16,2), XCD-swizzled;
// z-half computes a K=1024 partial of C = A*B^T into P{0,1} (f32).
// ---------------------------------------------------------------------------
__global__ __launch_bounds__(256) void gemm_bt_splitk(
    const ushort_t* __restrict__ A, const ushort_t* __restrict__ B,
    float* __restrict__ P0, float* __restrict__ P1)
{
  __shared__ ushort_t sA[128 * 32];
  __shared__ ushort_t sB[128 * 32];

  // XCD swizzle over the flattened 512-block grid
  const int id = (blockIdx.z * 16 + blockIdx.y) * 16 + blockIdx.x;
  const int sw = (id & 7) * 64 + (id >> 3);        // 0..511
  const int bx = sw & 15;
  const int by = (sw >> 4) & 15;
  const int bz = sw >> 8;

  const int K = Hc;
  const int tid  = threadIdx.x;
  const int lane = tid & 63;
  const int wid  = tid >> 6;
  const int wr   = wid >> 1;
  const int wc   = wid & 1;
  const int row0 = by * 128;
  const int col0 = bx * 128;
  const int koff = bz * 1024;
  float* C = bz ? P1 : P0;
  const int fr = lane & 15;
  const int fq = lane >> 4;

  f32x4 acc[4][4];
  #pragma unroll
  for (int m = 0; m < 4; ++m)
    #pragma unroll
    for (int n = 0; n < 4; ++n) acc[m][n] = (f32x4){0.f, 0.f, 0.f, 0.f};

  const int rS = tid >> 2;
  const int kg = (tid & 3) * 8;
  const ushort_t* Asrc0 = A + dsz(row0 + rS) * K + koff + kg;
  const ushort_t* Asrc1 = A + dsz(row0 + 64 + rS) * K + koff + kg;
  const ushort_t* Bsrc0 = B + dsz(col0 + rS) * K + koff + kg;
  const ushort_t* Bsrc1 = B + dsz(col0 + 64 + rS) * K + koff + kg;
  char* ldsA0 = (char*)sA + tid * 16;
  char* ldsA1 = (char*)sA + 4096 + tid * 16;
  char* ldsB0 = (char*)sB + tid * 16;
  char* ldsB1 = (char*)sB + 4096 + tid * 16;

  for (int k0 = 0; k0 < 1024; k0 += 32) {
    GL16(Asrc0 + k0, ldsA0);
    GL16(Asrc1 + k0, ldsA1);
    GL16(Bsrc0 + k0, ldsB0);
    GL16(Bsrc1 + k0, ldsB1);
    __syncthreads();

    bf16x8 a[4], b[4];
    #pragma unroll
    for (int m = 0; m < 4; ++m)
      a[m] = *(const bf16x8*)&sA[(wr * 64 + m * 16 + fr) * 32 + fq * 8];
    #pragma unroll
    for (int n = 0; n < 4; ++n)
      b[n] = *(const bf16x8*)&sB[(wc * 64 + n * 16 + fr) * 32 + fq * 8];
    #pragma unroll
    for (int m = 0; m < 4; ++m)
      #pragma unroll
      for (int n = 0; n < 4; ++n)
        acc[m][n] = __builtin_amdgcn_mfma_f32_16x16x32_bf16(a[m], b[n], acc[m][n], 0, 0, 0);
    __syncthreads();
  }

  #pragma unroll
  for (int m = 0; m < 4; ++m)
    #pragma unroll
    for (int n = 0; n < 4; ++n)
      #pragma unroll
      for (int j = 0; j < 4; ++j)
        C[dsz(row0 + wr * 64 + m * 16 + fq * 4 + j) * 2048 +
          col0 + wc * 64 + n * 16 + fr] = acc[m][n][j];
}

__global__ void add_partials(const float* __restrict__ P0, const float* __restrict__ P1,
                             float* __restrict__ out)
{
  int i = blockIdx.x * 256 + threadIdx.x;      // float4 index, 1M total
  float4 a = ((const float4*)P0)[i];
  float4 b = ((const float4*)P1)[i];
  float4 r; r.x = a.x + b.x; r.y = a.y + b.y; r.z = a.z + b.z; r.w = a.w + b.w;
  ((float4*)out)[i] = r;
}

// ---------------------------------------------------------------------------
// RoPE cos/sin table: tab[r][j] = (cos, sin) of pos[r] * invfreq[j].
// ---------------------------------------------------------------------------
__global__ void rope_tab(const int* __restrict__ pos, float2* __restrict__ tab)
{
  int idx = blockIdx.x * 256 + threadIdx.x;   // 131072
  int j = idx & 63;
  int r = idx >> 6;
  float p = (float)pos[r];
  float f = p * expf(-(float)j * ROPE_INV);
  float2 cs; cs.x = cosf(f); cs.y = sinf(f);
  tab[idx] = cs;
}

// RoPE in-place on bf16 qb, folds in QSCALE (table-driven).
__global__ void rope_q_ip(ushort_t* __restrict__ qb, const float2* __restrict__ tab)
{
  int idx = blockIdx.x * blockDim.x + threadIdx.x;   // 2M
  int j = idx & 63;
  int h = (idx >> 6) & 15;
  int r = idx >> 10;
  float2 cs = tab[r * 64 + j];
  ushort_t* d = qb + dsz(r) * (NHc * HDc) + h * HDc;
  float x1 = bf2f(d[j]), x2 = bf2f(d[j + 64]);
  d[j]      = f2bf((x1 * cs.x - x2 * cs.y) * QSCALE);
  d[j + 64] = f2bf((x2 * cs.x + x1 * cs.y) * QSCALE);
}

// RoPE self-k (bf16 in) -> Kcat rows 1024..2047 (table-driven)
__global__ void rope_k_kcat(const ushort_t* __restrict__ kkvb, const float2* __restrict__ tab,
                            ushort_t* __restrict__ Kcat)
{
  int idx = blockIdx.x * blockDim.x + threadIdx.x;   // 512K
  int j = idx & 63;
  int kvh = (idx >> 6) & 3;
  int s = (idx >> 8) & 1023;
  int b = idx >> 18;
  float2 cs = tab[(b * Sc + s) * 64 + j];
  const ushort_t* src = kkvb + dsz(b * Sc + s) * (NKVc * HDc) + kvh * HDc;
  ushort_t* dst = Kcat + (dsz(b * NKVc + kvh) * 2048 + 1024 + s) * HDc;
  float x1 = bf2f(src[j]), x2 = bf2f(src[j + 64]);
  dst[j]      = f2bf(x1 * cs.x - x2 * cs.y);
  dst[j + 64] = f2bf(x2 * cs.x + x1 * cs.y);
}

// kb_keys fp32 -> Kcat rows 0..1023 bf16
__global__ void kb_kcat(const float* __restrict__ src, ushort_t* __restrict__ Kcat)
{
  int i = blockIdx.x * blockDim.x + threadIdx.x;     // 262144
  int d4 = i & 31;
  int kvh = (i >> 5) & 3;
  int k = (i >> 7) & 1023;
  int b = i >> 17;
  float4 v = *(const float4*)&src[dsz(b * KBc + k) * (NKVc * HDc) + kvh * HDc + d4 * 4];
  ushort4 o;
  o.x = f2bf(v.x); o.y = f2bf(v.y); o.z = f2bf(v.z); o.w = f2bf(v.w);
  *(ushort4*)&Kcat[(dsz(b * NKVc + kvh) * 2048 + k) * HDc + d4 * 4] = o;
}

// Build Vt[b][kvh][128][2048] from kb_values (f32) + vkvb (bf16)
__global__ __launch_bounds__(256) void vt_build(const float* __restrict__ kbv,
                                                const ushort_t* __restrict__ vkvb,
                                                ushort_t* __restrict__ Vt)
{
  __shared__ float sT[32][33];
  const int k0 = blockIdx.x * 32;
  const int d0 = blockIdx.y * 32;
  const int bk = blockIdx.z;
  const int b = bk >> 2, kvh = bk & 3;
  const int tid = threadIdx.x;

  #pragma unroll
  for (int t = 0; t < 4; ++t) {
    int li = tid + t * 256;
    int kk = li >> 5, dl = li & 31;
    int kg = k0 + kk;
    float v = (kg < 1024)
      ? kbv[dsz(b * KBc + kg) * (NKVc * HDc) + kvh * HDc + d0 + dl]
      : bf2f(vkvb[dsz(b * Sc + kg - 1024) * (NKVc * HDc) + kvh * HDc + d0 + dl]);
    sT[kk][dl] = v;
  }
  __syncthreads();
  #pragma unroll
  for (int t = 0; t < 4; ++t) {
    int li = tid + t * 256;
    int dl = li >> 5, kk = li & 31;
    Vt[(dsz(b * NKVc + kvh) * HDc + d0 + dl) * 2048 + k0 + kk] = f2bf(sT[kk][dl]);
  }
}

// ---------------------------------------------------------------------------
// Attention v6 (R8-proven, 63us): 512-thread blocks (8 waves x 16q = 128 q)
// sharing one 32KB K/V double-buffer; 3-way inter-block KV split.
// __launch_bounds__(512, 2) -- no VGPR cap (R7's (512,6) spilled).
// ---------------------------------------------------------------------------
__global__ __launch_bounds__(512, 2) void attn_mfma6(
    const ushort_t* __restrict__ Qr,   // roped q (pre-scaled), (B*S, 2048)
    const ushort_t* __restrict__ Qn,   // q_new (pre-scaled), (B*S, 2048)
    const ushort_t* __restrict__ Kcat, // (B, NKV, 2048, 128)
    const ushort_t* __restrict__ Vt,   // (B, NKV, 128, 2048)
    ushort_t* __restrict__ Opart,      // [3][256][128][128] bf16
    float* __restrict__ mlpart)        // [3][256][128][2]
{
  __shared__ ushort_t sK[2][32 * 128];   // 8KB/buf, rows XOR-swizzled
  __shared__ ushort_t sV[2][128 * 32];   // 8KB/buf, slots XOR-swizzled

  const int tid = threadIdx.x;
  const int lane = tid & 63;
  const int w = tid >> 6;                // 0..7
  const int fr = lane & 15;
  const int fq = lane >> 4;
  const int blk = blockIdx.x;            // (b,h,qt): qt 0..7
  const int third = blockIdx.y;          // 0..2
  const int qt = blk & 7;
  const int h  = (blk >> 3) & 15;
  const int b  = blk >> 7;
  const int kvh = h >> 2;
  const int qrow = qt * 128 + w * 16 + fr;
  const int kperm = ((fr >> 2) << 3) + (fr & 3);   // u(kperm) = fr

  const ushort_t* Kb = Kcat + dsz(b * NKVc + kvh) * 2048 * HDc;
  const ushort_t* Vb = Vt   + dsz(b * NKVc + kvh) * HDc * 2048;

  const int nt  = 36 + 4 * qt;           // key tiles (keys = 1024 + (qt+1)*128)
  const int q3 = nt / 3, r3 = nt % 3;
  const int t_lo = third * q3 + (third < r3 ? third : r3);
  const int t_hi = t_lo + q3 + (third < r3 ? 1 : 0);

  // staging offsets: 512 threads cover one 8KB tile each for K and V.
  const int krr = tid >> 4;
  const int kss = tid & 15;
  const int kuu = (krr & 3) | ((krr >> 3) << 2);
  const int kOff = krr * 256 + ((kss ^ kuu) * 16);
  const int vrr = tid >> 2;
  const int vss = tid & 3;
  const size_t vOff = (size_t)vrr * 4096 + (((vss ^ ((vrr >> 1) & 3))) * 16);

  const int vslot = (fq ^ ((fr >> 1) & 3)) * 8;

#define STAGE(bi, t)                                                   \
  {                                                                    \
    const char* kgb = (const char*)Kb + (size_t)(t) * 8192;            \
    const char* vgb = (const char*)Vb + (size_t)(t) * 64;              \
    GL16(kgb + kOff, (char*)&sK[bi][0] + tid * 16);                    \
    GL16(vgb + vOff, (char*)&sV[bi][0] + tid * 16);                    \
  }

  // Q fragments for the starting phase
  bf16x8 qf[4];
  {
    const ushort_t* qp = (t_lo >= 32 ? Qr : Qn) + dsz(b * Sc + qrow) * (NHc * HDc) + h * HDc;
    #pragma unroll
    for (int c = 0; c < 4; ++c) qf[c] = *(const bf16x8*)&qp[c * 32 + fq * 8];
  }

  float m = -1e30f, l = 0.f;
  f32x4 ot[8];
  #pragma unroll
  for (int dt = 0; dt < 8; ++dt) ot[dt] = (f32x4){0.f, 0.f, 0.f, 0.f};

  STAGE(0, t_lo);
  __syncthreads();

  for (int t = t_lo; t < t_hi; ++t) {
    const int cur = (t - t_lo) & 1;
    if (t + 1 < t_hi) STAGE(cur ^ 1, t + 1);

    if (t == 32) {   // phase switch: self keys use roped q
      const ushort_t* qp = Qr + dsz(b * Sc + qrow) * (NHc * HDc) + h * HDc;
      #pragma unroll
      for (int c = 0; c < 4; ++c) qf[c] = *(const bf16x8*)&qp[c * 32 + fq * 8];
    }
    const bool self = (t >= 32);

    // fragments from LDS (swizzle undone at read)
    bf16x8 ka0[4], ka1[4], va[8];
    #pragma unroll
    for (int c = 0; c < 4; ++c) {
      const int ks = ((c * 4 + fq) ^ fr) * 8;
      ka0[c] = *(const bf16x8*)&sK[cur][kperm * 128 + ks];
      ka1[c] = *(const bf16x8*)&sK[cur][(kperm + 4) * 128 + ks];
    }
    #pragma unroll
    for (int dt = 0; dt < 8; ++dt)
      va[dt] = *(const bf16x8*)&sV[cur][(dt * 16 + fr) * 32 + vslot];

    f32x4 s0 = (f32x4){0.f, 0.f, 0.f, 0.f};
    f32x4 s1 = (f32x4){0.f, 0.f, 0.f, 0.f};
    #pragma unroll
    for (int c = 0; c < 4; ++c)
      s0 = __builtin_amdgcn_mfma_f32_16x16x32_bf16(ka0[c], qf[c], s0, 0, 0, 0);
    #pragma unroll
    for (int c = 0; c < 4; ++c)
      s1 = __builtin_amdgcn_mfma_f32_16x16x32_bf16(ka1[c], qf[c], s1, 0, 0, 0);

    if (self) {
      #pragma unroll
      for (int j = 0; j < 4; ++j) {
        s0[j] = (t * 32 + fq * 8 + j     - 1024 > qrow) ? -1e30f : s0[j];
        s1[j] = (t * 32 + fq * 8 + 4 + j - 1024 > qrow) ? -1e30f : s1[j];
      }
    }
    float tmax = fmaxf(fmaxf(fmaxf(s0[0], s0[1]), fmaxf(s0[2], s0[3])),
                       fmaxf(fmaxf(s1[0], s1[1]), fmaxf(s1[2], s1[3])));
    tmax = fmaxf(tmax, __shfl_xor(tmax, 16));
    tmax = fmaxf(tmax, __shfl_xor(tmax, 32));

    if (__any(tmax > m + 8.f)) {                 // defer-max (T13)
      float mnew = fmaxf(m, tmax);
      float corr = exp2f(m - mnew);
      l *= corr;
      #pragma unroll
      for (int dt = 0; dt < 8; ++dt) {
        ot[dt][0] *= corr; ot[dt][1] *= corr;
        ot[dt][2] *= corr; ot[dt][3] *= corr;
      }
      m = mnew;
    }
    float ps = 0.f;
    bf16x8 pb;
    #pragma unroll
    for (int j = 0; j < 4; ++j) { float p = exp2f(s0[j] - m); ps += p; pb[j] = (__bf16)p; }
    #pragma unroll
    for (int j = 0; j < 4; ++j) { float p = exp2f(s1[j] - m); ps += p; pb[j + 4] = (__bf16)p; }
    l += ps;

    #pragma unroll
    for (int dt = 0; dt < 8; ++dt)
      ot[dt] = __builtin_amdgcn_mfma_f32_16x16x32_bf16(va[dt], pb, ot[dt], 0, 0, 0);

    __syncthreads();   // drains staging loads; safe buffer swap
  }
#undef STAGE

  // full per-query l (sum over fq lanes)
  l += __shfl_xor(l, 16);
  l += __shfl_xor(l, 32);

  // write partials (O unnormalized bf16; m,l f32)
  const int qin = w * 16 + fr;               // 0..127
  ushort_t* ob = Opart + (dsz(third * 256 + blk) * 128 + qin) * 128;
  #pragma unroll
  for (int dt = 0; dt < 8; ++dt) {
    ushort_t o4a[4];
    #pragma unroll
    for (int j = 0; j < 4; ++j) o4a[j] = f2bf(ot[dt][j]);
    *(ushort4*)&ob[dt * 16 + fq * 4] = *(ushort4*)o4a;
  }
  if (fq == 0) {
    float* mlp = mlpart + (dsz(third * 256 + blk) * 128 + qin) * 2;
    mlp[0] = m;
    mlp[1] = l;
  }
}

// ---------------------------------------------------------------------------
// Merge the 3 KV-split partials -> attnb bf16.
// ---------------------------------------------------------------------------
__global__ void attn_merge(const ushort_t* __restrict__ Opart,
                           const float* __restrict__ mlpart,
                           ushort_t* __restrict__ attnb)
{
  const int i = blockIdx.x * 256 + threadIdx.x;    // 8-elem group index
  const int e = i * 8;
  const int qg = e >> 7;          // (blk256, qin): 0..32767
  const int d0 = e & 127;
  const int blk = qg >> 7;        // 0..255
  const int qin = qg & 127;
  const int qt = blk & 7;
  const int h  = (blk >> 3) & 15;
  const int b  = blk >> 7;

  float mm[3], ll[3];
  #pragma unroll
  for (int p = 0; p < 3; ++p) {
    const float* ml = mlpart + (dsz(p * 256 + blk) * 128 + qin) * 2;
    mm[p] = ml[0]; ll[p] = ml[1];
  }
  float M = fmaxf(fmaxf(mm[0], mm[1]), mm[2]);
  float sc[3], L = 0.f;
  #pragma unroll
  for (int p = 0; p < 3; ++p) { sc[p] = exp2f(mm[p] - M); L += ll[p] * sc[p]; }
  const float Linv = 1.f / L;
  #pragma unroll
  for (int p = 0; p < 3; ++p) sc[p] *= Linv;

  float acc[8];
  #pragma unroll
  for (int j = 0; j < 8; ++j) acc[j] = 0.f;
  #pragma unroll
  for (int p = 0; p < 3; ++p) {
    const ushort_t* o = Opart + (dsz(p * 256 + blk) * 128 + qin) * 128 + d0;
    ushort4 a0 = *(const ushort4*)&o[0];
    ushort4 a1 = *(const ushort4*)&o[4];
    acc[0] += bf2f(a0.x) * sc[p]; acc[1] += bf2f(a0.y) * sc[p];
    acc[2] += bf2f(a0.z) * sc[p]; acc[3] += bf2f(a0.w) * sc[p];
    acc[4] += bf2f(a1.x) * sc[p]; acc[5] += bf2f(a1.y) * sc[p];
    acc[6] += bf2f(a1.z) * sc[p]; acc[7] += bf2f(a1.w) * sc[p];
  }

  ushort_t r[8];
  #pragma unroll
  for (int j = 0; j < 8; ++j) r[j] = f2bf(acc[j]);
  ushort_t* dst = attnb + dsz(b * Sc + qt * 128 + qin) * (NHc * HDc) + h * HDc + d0;
  *(ushort4*)&dst[0] = *(ushort4*)&r[0];
  *(ushort4*)&dst[4] = *(ushort4*)&r[4];
}

// ---------------------------------------------------------------------------
// Launch
// ---------------------------------------------------------------------------
extern "C" void kernel_launch(void* const* d_in, const int* in_sizes, int n_in,
                              void* d_out, int out_size, void* d_ws, size_t ws_size,
                              hipStream_t stream)
{
  const float* x    = (const float*)d_in[0];
  const int*   pos  = (const int*)d_in[2];
  const float* kbk  = (const float*)d_in[3];
  const float* kbv  = (const float*)d_in[4];
  const float* Wq   = (const float*)d_in[5];
  const float* Wqn  = (const float*)d_in[6];
  const float* Wk   = (const float*)d_in[7];
  const float* Wv   = (const float*)d_in[8];
  const float* Wo   = (const float*)d_in[9];
  float* out = (float*)d_out;

  const size_t MU = 1048576;

  ushort_t* U = (ushort_t*)d_ws;
  ushort_t* xb    = U;                 // 4M u
  ushort_t* Wqb   = U + 4  * MU;       // 4M
  ushort_t* Wqnb  = U + 8  * MU;       // 4M
  ushort_t* Wkb   = U + 12 * MU;       // 1M
  ushort_t* Wvb   = U + 13 * MU;       // 1M
  ushort_t* Wob   = U + 14 * MU;       // 4M
  ushort_t* qb    = U + 18 * MU;       // 4M (roped in-place -> Qr)
  ushort_t* qnb   = U + 22 * MU;       // 4M (pre-scaled)
  ushort_t* kkvb  = U + 26 * MU;       // 1M
  ushort_t* vkvb  = U + 27 * MU;       // 1M
  ushort_t* Kcat  = U + 28 * MU;       // 2M
  ushort_t* Vt    = U + 30 * MU;       // 2M
  ushort_t* attnb = U + 32 * MU;       // 4M  -> total 36M u = 72 MB
  // aliases (regions dead at the time they're written):
  ushort_t* Opart  = U;                        // 12M u (xb..Wqnb, dead after gemm_proj)
  float*    mlpart = (float*)(U + 26 * MU);    // 786KB (kkvb, dead after rope_k_kcat)
  float2*   ropet  = (float2*)(U + 12 * MU);   // 1MB (Wkb, dead after gemm_proj)
  // split-K partials for the Wo GEMM (dead regions at Wo-GEMM time):
  float*    P0     = (float*)U;                // 16MB (Opart dead after attn_merge)
  float*    P1     = (float*)(U + 18 * MU);    // 16MB (qb/qnb dead after attention)

  dim3 blk(256);

  conv_all<<<18432, blk, 0, stream>>>(x, Wq, Wqn, Wk, Wv, Wo,
                                      xb, Wqb, Wqnb, Wkb, Wvb, Wob);
  gemm_proj<<<dim3(40, 16), blk, 0, stream>>>(xb, Wqb, Wqnb, Wkb, Wvb,
                                              qb, qnb, kkvb, vkvb);
  rope_tab<<<512, blk, 0, stream>>>(pos, ropet);
  rope_q_ip<<<8192, blk, 0, stream>>>(qb, ropet);
  kb_kcat<<<1024, blk, 0, stream>>>(kbk, Kcat);
  rope_k_kcat<<<2048, blk, 0, stream>>>(kkvb, ropet, Kcat);
  vt_build<<<dim3(64, 4, 8), blk, 0, stream>>>(kbv, vkvb, Vt);
  // attention: (b,h,qt) x third grid, 8 waves x 16q, KV-split partials
  attn_mfma6<<<dim3(256, 3), dim3(512), 0, stream>>>(qb, qnb, Kcat, Vt, Opart, mlpart);
  attn_merge<<<2048, blk, 0, stream>>>(Opart, mlpart, attnb);
  // Wo projection, 2-way split-K + f32 add
  gemm_bt_splitk<<<dim3(16, 16, 2), blk, 0, stream>>>(attnb, Wob, P0, P1);
  add_partials<<<4096, blk, 0, stream>>>(P0, P1, out);
}